// Round 2
// baseline (7170.634 us; speedup 1.0000x reference)
//
#include <hip/hip_runtime.h>
#include <math.h>

// ---------------- constants ----------------
#define BB    2
#define HH    96
#define WW    96
#define CC    256
#define NHEAD 8
#define DH    32
#define NN    (HH*WW)          // 9216
#define NWIN  (BB*NN)          // 18432 windows of 9 tokens
#define NTOK  (NWIN*9)         // 165888 tokens
#define FF    1024

typedef __attribute__((ext_vector_type(8))) short short8;
typedef __attribute__((ext_vector_type(4))) float floatx4;

__device__ __forceinline__ float bf2f(unsigned short u) {
    union { unsigned int i; float f; } c; c.i = ((unsigned int)u) << 16; return c.f;
}
__device__ __forceinline__ unsigned short f2bf(float f) {
    union { unsigned int i; float f; } c; c.f = f;
    unsigned int i = c.i;
    return (unsigned short)((i + 0x7FFFu + ((i >> 16) & 1u)) >> 16);
}
__device__ __forceinline__ float gelu_f(float v) {
    float y = 0.7978845608028654f * (v + 0.044715f * v * v * v);
    float t = 1.f - 2.f / (1.f + __expf(2.f * y));   // tanh(y)
    return 0.5f * v * (1.f + t);
}
// token t=(b, n=h*W+w, kk=r*3+c) -> physical output row (b, 3h+r, 3w+c)
__device__ __forceinline__ size_t prow(int t) {
    int b = t / (NN * 9);
    int r9 = t - b * (NN * 9);
    int n = r9 / 9, kk = r9 - n * 9;
    int h = n / WW, w = n - h * WW;
    int rr = kk / 3, c3 = kk - rr * 3;
    return ((size_t)b * (3 * HH) + 3 * h + rr) * (3 * WW) + 3 * w + c3;
}

// ---------------- GEMM: out[M,N] = A[M,K] @ B[K,N] + bias, epilogue variants ----
// A: bf16 (ushort) or fp32 per ABF16. B: fp32 row-major [K,N] (converted to bf16
// while staging). M,N,K multiples of 64 (no bounds checks).
enum { EPI_F32 = 0, EPI_BF16 = 1, EPI_GELU = 2, EPI_RESID = 3, EPI_BF16PE = 4 };

template <int EPI, bool ABF16>
__global__ __launch_bounds__(256) void gemm_k(const void* __restrict__ Ap,
                                              const float* __restrict__ Bp,
                                              const float* __restrict__ bias,
                                              void* __restrict__ outp,
                                              int M, int N, int K, int row_off,
                                              const float* __restrict__ sp,
                                              const float* __restrict__ Epe) {
    __shared__ __align__(16) unsigned short As[64 * 32];
    __shared__ __align__(16) unsigned short Bs[64 * 32];

    const int tid  = threadIdx.x;
    const int row0 = blockIdx.y * 64;
    const int col0 = blockIdx.x * 64;
    const int wave = tid >> 6, lane = tid & 63;
    const int wm = wave >> 1, wn = wave & 1;     // 2x2 waves of 32x32
    const int lr = lane & 15, quad = lane >> 4;
    const int k0 = quad * 8;

    floatx4 acc[2][2] = {};

    for (int kt = 0; kt < K; kt += 32) {
        // stage A tile (64 x 32) as bf16
        if (ABF16) {
            const unsigned int* Ag = (const unsigned int*)Ap;
            unsigned int* AsU = (unsigned int*)As;
#pragma unroll
            for (int i = 0; i < 4; i++) {
                int u = tid + i * 256;
                int r = u >> 4, c2 = u & 15;
                AsU[r * 16 + c2] = Ag[(size_t)(row0 + r) * (K >> 1) + (kt >> 1) + c2];
            }
        } else {
            const float* Ag = (const float*)Ap;
#pragma unroll
            for (int i = 0; i < 8; i++) {
                int e = tid + i * 256;
                int r = e >> 5, c = e & 31;
                As[r * 32 + c] = f2bf(Ag[(size_t)(row0 + r) * K + kt + c]);
            }
        }
        // stage B tile (32 x 64) transposed into Bs[n][k], bf16
#pragma unroll
        for (int i = 0; i < 8; i++) {
            int e = tid + i * 256;
            int kr = e >> 6, nc = e & 63;
            Bs[nc * 32 + kr] = f2bf(Bp[(size_t)(kt + kr) * N + col0 + nc]);
        }
        __syncthreads();

        short8 af[2], bf[2];
#pragma unroll
        for (int mt = 0; mt < 2; mt++)
            af[mt] = *(const short8*)&As[(wm * 32 + mt * 16 + lr) * 32 + k0];
#pragma unroll
        for (int nt = 0; nt < 2; nt++)
            bf[nt] = *(const short8*)&Bs[(wn * 32 + nt * 16 + lr) * 32 + k0];
#pragma unroll
        for (int mt = 0; mt < 2; mt++)
#pragma unroll
            for (int nt = 0; nt < 2; nt++)
                acc[mt][nt] = __builtin_amdgcn_mfma_f32_16x16x32_bf16(
                    af[mt], bf[nt], acc[mt][nt], 0, 0, 0);
        __syncthreads();
    }

    // epilogue: C/D layout col=lane&15, row=quad*4+reg  [verified m89/m91]
#pragma unroll
    for (int mt = 0; mt < 2; mt++) {
#pragma unroll
        for (int nt = 0; nt < 2; nt++) {
            int colg = col0 + wn * 32 + nt * 16 + lr;
            int rowb = row0 + wm * 32 + mt * 16 + quad * 4;
            float bv = bias[colg];
#pragma unroll
            for (int r = 0; r < 4; r++) {
                float v = acc[mt][nt][r] + bv;
                if (EPI == EPI_F32) {
                    ((float*)outp)[(size_t)(rowb + r) * N + colg] = v;
                } else if (EPI == EPI_BF16) {
                    ((unsigned short*)outp)[(size_t)(rowb + r) * N + colg] = f2bf(v);
                } else if (EPI == EPI_GELU) {
                    ((unsigned short*)outp)[(size_t)(rowb + r) * N + colg] = f2bf(gelu_f(v));
                } else if (EPI == EPI_RESID) {
                    // fp32 accumulate into permuted residual stream (N == CC)
                    size_t pr = prow(row_off + rowb + r);
                    ((float*)outp)[pr * N + colg] += v;
                } else {  // EPI_BF16PE: rank-2 positional correction (N == CC)
                    int t = rowb + r;
                    float gx = sp[(size_t)t * 2], gy = sp[(size_t)t * 2 + 1];
                    v += gx * Epe[colg] + gy * Epe[CC + colg];
                    ((unsigned short*)outp)[(size_t)t * N + colg] = f2bf(v);
                }
            }
        }
    }
}

// ---------------- E/f precompute: E = ppw @ W (2xC), f = ppb @ W + b (C) -------
// block 0 -> (Wq,bq) into buf[0:3C]; block 1 -> (Wk,bk) into buf[3C:6C]
__global__ __launch_bounds__(256) void ef_k(const float* __restrict__ Wq,
                                            const float* __restrict__ bq,
                                            const float* __restrict__ Wk,
                                            const float* __restrict__ bk,
                                            const float* __restrict__ ppw,
                                            const float* __restrict__ ppb,
                                            float* __restrict__ buf) {
    const float* W = blockIdx.x ? Wk : Wq;
    const float* bs = blockIdx.x ? bk : bq;
    float* o = buf + (size_t)blockIdx.x * 3 * CC;
    int c = threadIdx.x;
    float e0 = 0.f, e1 = 0.f, f = 0.f;
    for (int k = 0; k < CC; k++) {
        float w = W[(size_t)k * CC + c];
        e0 += ppw[k] * w;
        e1 += ppw[CC + k] * w;
        f  += ppb[k] * w;
    }
    o[c] = e0; o[CC + c] = e1; o[2 * CC + c] = f + bs[c];
}

// ---------------- bilinear sample + positional encoding -----------------------
// token t: grid = sp[t]; sample xmap[B,H,W,C]; add pe; write xw[P(t)] (fp32).
__global__ __launch_bounds__(256) void sample_k(const float* __restrict__ xmap,
                                                const float* __restrict__ sp,
                                                const float* __restrict__ ppw,
                                                const float* __restrict__ ppb,
                                                float* __restrict__ xw) {
    int t = blockIdx.x * 4 + (threadIdx.x >> 6);
    int lane = threadIdx.x & 63;
    int b = t / (NN * 9);

    const float* g = sp + (size_t)t * 2;
    float gxr = g[0], gyr = g[1];
    float gx = (gxr + 1.f) * (WW * 0.5f) - 0.5f;
    float gy = (gyr + 1.f) * (HH * 0.5f) - 0.5f;
    float x0f = floorf(gx), y0f = floorf(gy);
    int x0 = (int)x0f, y0 = (int)y0f;
    float wx1 = gx - x0f, wx0 = 1.f - wx1;
    float wy1 = gy - y0f, wy0 = 1.f - wy1;

    int ch = lane * 4;
    float a0 = 0.f, a1 = 0.f, a2 = 0.f, a3 = 0.f;
#pragma unroll
    for (int cc = 0; cc < 4; cc++) {
        int xx = x0 + (cc & 1), yy = y0 + (cc >> 1);
        float wgt = ((cc & 1) ? wx1 : wx0) * ((cc >> 1) ? wy1 : wy0);
        bool valid = (xx >= 0) && (xx < WW) && (yy >= 0) && (yy < HH);
        float m = valid ? wgt : 0.f;
        int xc = min(max(xx, 0), WW - 1), yc = min(max(yy, 0), HH - 1);
        const float* src = xmap + (((size_t)b * HH + yc) * WW + xc) * CC + ch;
        float4 vv = *(const float4*)src;
        a0 += m * vv.x; a1 += m * vv.y; a2 += m * vv.z; a3 += m * vv.w;
    }
    float p0 = gxr * ppw[ch + 0] + gyr * ppw[CC + ch + 0] + ppb[ch + 0];
    float p1 = gxr * ppw[ch + 1] + gyr * ppw[CC + ch + 1] + ppb[ch + 1];
    float p2 = gxr * ppw[ch + 2] + gyr * ppw[CC + ch + 2] + ppb[ch + 2];
    float p3 = gxr * ppw[ch + 3] + gyr * ppw[CC + ch + 3] + ppb[ch + 3];

    size_t o = prow(t) * CC + ch;
    float4 out; out.x = a0 + p0; out.y = a1 + p1; out.z = a2 + p2; out.w = a3 + p3;
    *(float4*)(xw + o) = out;
}

// ---------------- layernorm: 1 wave per 256-wide row ---------------------------
// reads xw[P(row)] (fp32, permuted), writes hh[row] (bf16, token order)
__global__ __launch_bounds__(256) void ln_k(const float* __restrict__ xw,
                                            const float* __restrict__ gamma,
                                            const float* __restrict__ beta,
                                            unsigned short* __restrict__ hh) {
    int row = blockIdx.x * 4 + (threadIdx.x >> 6);
    int lane = threadIdx.x & 63;
    size_t pr = prow(row);
    float4 xv = *(const float4*)(xw + pr * CC + lane * 4);
    float s = xv.x + xv.y + xv.z + xv.w;
    float sq = xv.x * xv.x + xv.y * xv.y + xv.z * xv.z + xv.w * xv.w;
#pragma unroll
    for (int off = 32; off; off >>= 1) {
        s += __shfl_xor(s, off);
        sq += __shfl_xor(sq, off);
    }
    float mean = s * (1.f / CC);
    float var = fmaxf(sq * (1.f / CC) - mean * mean, 0.f);
    float rs = rsqrtf(var + 1e-5f);

    float xs[4] = {xv.x, xv.y, xv.z, xv.w};
    ushort4 ho;
    unsigned short* hop = (unsigned short*)&ho;
#pragma unroll
    for (int ci = 0; ci < 4; ci++) {
        int c = lane * 4 + ci;
        hop[ci] = f2bf((xs[ci] - mean) * rs * gamma[c] + beta[c]);
    }
    *(ushort4*)(hh + (size_t)row * CC + lane * 4) = ho;
}

// ---------------- windowed attention: 1 wave per (b,n) window ------------------
// o may alias q: each (i,h) lane reads only its own 32-ch q slice then writes
// the same slice; k,v staged to LDS before any write.
__global__ __launch_bounds__(64) void attn_k(const unsigned short* q,
                                             const unsigned short* __restrict__ k,
                                             const unsigned short* __restrict__ v,
                                             unsigned short* o) {
    __shared__ __align__(16) unsigned short ks[9 * CC];
    __shared__ __align__(16) unsigned short vs[9 * CC];
    int w = blockIdx.x;
    int lane = threadIdx.x;
    size_t base = (size_t)w * 9;
    const unsigned int* kg = (const unsigned int*)k;
    const unsigned int* vg = (const unsigned int*)v;
    unsigned int* ksu = (unsigned int*)ks;
    unsigned int* vsu = (unsigned int*)vs;
    for (int idx = lane; idx < 9 * CC / 2; idx += 64) {
        ksu[idx] = kg[base * (CC / 2) + idx];
        vsu[idx] = vg[base * (CC / 2) + idx];
    }
    __syncthreads();

    const float scale = 0.17677669529663687f;  // 1/sqrt(32)
    const unsigned int* qg = (const unsigned int*)q;
    unsigned int* og = (unsigned int*)o;

    for (int p = lane; p < 72; p += 64) {
        int i = p >> 3;        // q token in window, 0..8
        int h = p & 7;         // head
        float qv[DH];
#pragma unroll
        for (int d2 = 0; d2 < DH / 2; d2++) {
            unsigned int u = qg[(base + i) * (CC / 2) + h * (DH / 2) + d2];
            qv[2 * d2] = bf2f((unsigned short)(u & 0xffff));
            qv[2 * d2 + 1] = bf2f((unsigned short)(u >> 16));
        }
        float sc[9];
        float mx = -1e30f;
#pragma unroll
        for (int j = 0; j < 9; j++) {
            float s = 0.f;
#pragma unroll
            for (int d2 = 0; d2 < DH / 2; d2++) {
                unsigned int u = ksu[j * (CC / 2) + h * (DH / 2) + d2];
                s += qv[2 * d2] * bf2f((unsigned short)(u & 0xffff));
                s += qv[2 * d2 + 1] * bf2f((unsigned short)(u >> 16));
            }
            sc[j] = s * scale;
            mx = fmaxf(mx, sc[j]);
        }
        float den = 0.f;
#pragma unroll
        for (int j = 0; j < 9; j++) { sc[j] = __expf(sc[j] - mx); den += sc[j]; }
        float inv = 1.f / den;
#pragma unroll
        for (int j = 0; j < 9; j++) sc[j] *= inv;

#pragma unroll
        for (int d2 = 0; d2 < DH / 2; d2++) {
            float acc0 = 0.f, acc1 = 0.f;
#pragma unroll
            for (int j = 0; j < 9; j++) {
                unsigned int u = vsu[j * (CC / 2) + h * (DH / 2) + d2];
                acc0 += sc[j] * bf2f((unsigned short)(u & 0xffff));
                acc1 += sc[j] * bf2f((unsigned short)(u >> 16));
            }
            unsigned int pk = (unsigned int)f2bf(acc0) | ((unsigned int)f2bf(acc1) << 16);
            og[(base + i) * (CC / 2) + h * (DH / 2) + d2] = pk;
        }
    }
}

// ---------------- launcher ------------------------------------------------------
extern "C" void kernel_launch(void* const* d_in, const int* in_sizes, int n_in,
                              void* d_out, int out_size, void* d_ws, size_t ws_size,
                              hipStream_t stream) {
    const float* input = (const float*)d_in[0];
    const float* sp    = (const float*)d_in[1];
    const float* ipw   = (const float*)d_in[2];
    const float* ipb   = (const float*)d_in[3];
    const float* ppw   = (const float*)d_in[4];
    const float* ppb   = (const float*)d_in[5];
    const float* wq = (const float*)d_in[6];
    const float* bq = (const float*)d_in[7];
    const float* wk = (const float*)d_in[8];
    const float* bk = (const float*)d_in[9];
    const float* wv = (const float*)d_in[10];
    const float* bv = (const float*)d_in[11];
    const float* wo = (const float*)d_in[12];
    const float* bo = (const float*)d_in[13];
    const float* l1g = (const float*)d_in[14];
    const float* l1b = (const float*)d_in[15];
    const float* l2g = (const float*)d_in[16];
    const float* l2b = (const float*)d_in[17];
    const float* w1 = (const float*)d_in[18];
    const float* b1 = (const float*)d_in[19];
    const float* w2 = (const float*)d_in[20];
    const float* b2 = (const float*)d_in[21];

    // residual stream lives in d_out, rows permuted by prow()
    float* xw = (float*)d_out;

    // workspace layout (total ~324 MB):
    //   [0, SZ_BF)        hh (bf16)   -- xmap (fp32, 18.9MB) overlays here first
    //   [SZ_BF, 2SZ_BF)   qb          -- FFN mid (170MB/chunk) overlays qb+kb
    //   [2SZ_BF, 3SZ_BF)  kb
    //   [3SZ_BF, 4SZ_BF)  vb
    //   [4SZ_BF, +6KB)    E/f buffer
    const size_t SZ_BF = (size_t)NTOK * CC * 2;  // 84,934,656
    char* ws = (char*)d_ws;
    float* xmap         = (float*)ws;
    unsigned short* hh  = (unsigned short*)ws;
    unsigned short* qb  = (unsigned short*)(ws + SZ_BF);
    unsigned short* kb  = (unsigned short*)(ws + 2 * SZ_BF);
    unsigned short* vb  = (unsigned short*)(ws + 3 * SZ_BF);
    unsigned short* mid = (unsigned short*)(ws + SZ_BF);   // overlays qb,kb
    float* efbuf        = (float*)(ws + 4 * SZ_BF);

    // 1. input projection: [B*N, C] @ [C,C] -> xmap fp32 (plain row order)
    gemm_k<EPI_F32, false><<<dim3(CC / 64, (BB * NN) / 64), 256, 0, stream>>>(
        input, ipw, ipb, xmap, BB * NN, CC, CC, 0, nullptr, nullptr);
    // 2. bilinear sample + pe -> xw (permuted rows)
    sample_k<<<NTOK / 4, 256, 0, stream>>>(xmap, sp, ppw, ppb, xw);

    const int MC = NTOK / 2;  // FFN chunk rows (82944, mult of 64)
    for (int l = 0; l < 2; l++) {
        const float* WQ = wq + (size_t)l * CC * CC;
        const float* WK = wk + (size_t)l * CC * CC;
        const float* WV = wv + (size_t)l * CC * CC;
        const float* WO = wo + (size_t)l * CC * CC;
        const float* W1 = w1 + (size_t)l * CC * FF;
        const float* W2 = w2 + (size_t)l * FF * CC;

        ef_k<<<2, 256, 0, stream>>>(WQ, bq + l * CC, WK, bk + l * CC, ppw, ppb, efbuf);
        ln_k<<<NTOK / 4, 256, 0, stream>>>(xw, l1g + l * CC, l1b + l * CC, hh);
        gemm_k<EPI_BF16PE, true><<<dim3(CC / 64, NTOK / 64), 256, 0, stream>>>(
            hh, WQ, efbuf + 2 * CC, qb, NTOK, CC, CC, 0, sp, efbuf);
        gemm_k<EPI_BF16PE, true><<<dim3(CC / 64, NTOK / 64), 256, 0, stream>>>(
            hh, WK, efbuf + 5 * CC, kb, NTOK, CC, CC, 0, sp, efbuf + 3 * CC);
        gemm_k<EPI_BF16, true><<<dim3(CC / 64, NTOK / 64), 256, 0, stream>>>(
            hh, WV, bv + l * CC, vb, NTOK, CC, CC, 0, nullptr, nullptr);
        attn_k<<<NWIN, 64, 0, stream>>>(qb, kb, vb, qb);  // o in-place over q
        gemm_k<EPI_RESID, true><<<dim3(CC / 64, NTOK / 64), 256, 0, stream>>>(
            qb, WO, bo + l * CC, xw, NTOK, CC, CC, 0, nullptr, nullptr);
        ln_k<<<NTOK / 4, 256, 0, stream>>>(xw, l2g + l * CC, l2b + l * CC, hh);
        for (int cch = 0; cch < 2; cch++) {
            int m0 = cch * MC;
            gemm_k<EPI_GELU, true><<<dim3(FF / 64, MC / 64), 256, 0, stream>>>(
                hh + (size_t)m0 * CC, W1, b1 + l * FF, mid, MC, FF, CC, 0, nullptr, nullptr);
            gemm_k<EPI_RESID, true><<<dim3(CC / 64, MC / 64), 256, 0, stream>>>(
                mid, W2, b2 + l * CC, xw, MC, CC, FF, m0, nullptr, nullptr);
        }
    }
}

// Round 3
// 3531.334 us; speedup vs baseline: 2.0306x; 2.0306x over previous
//
#include <hip/hip_runtime.h>
#include <math.h>

// ---------------- constants ----------------
#define BB    2
#define HH    96
#define WW    96
#define CC    256
#define NHEAD 8
#define DH    32
#define NN    (HH*WW)          // 9216
#define NWIN  (BB*NN)          // 18432 windows of 9 tokens
#define NTOK  (NWIN*9)         // 165888 tokens
#define FF    1024

typedef __attribute__((ext_vector_type(8))) short short8;
typedef __attribute__((ext_vector_type(4))) float floatx4;

__device__ __forceinline__ float bf2f(unsigned short u) {
    union { unsigned int i; float f; } c; c.i = ((unsigned int)u) << 16; return c.f;
}
__device__ __forceinline__ unsigned short f2bf(float f) {
    union { unsigned int i; float f; } c; c.f = f;
    unsigned int i = c.i;
    return (unsigned short)((i + 0x7FFFu + ((i >> 16) & 1u)) >> 16);
}
__device__ __forceinline__ unsigned int pack2(float a, float b) {
    return (unsigned int)f2bf(a) | ((unsigned int)f2bf(b) << 16);
}
__device__ __forceinline__ float gelu_f(float v) {
    float y = 0.7978845608028654f * (v + 0.044715f * v * v * v);
    float t = 1.f - 2.f / (1.f + __expf(2.f * y));   // tanh(y)
    return 0.5f * v * (1.f + t);
}
__device__ __forceinline__ void unp(unsigned int u, float& a, float& b) {
    a = bf2f((unsigned short)(u & 0xffff));
    b = bf2f((unsigned short)(u >> 16));
}
// token t=(b, n=h*W+w, kk=r*3+c) -> physical output row (b, 3h+r, 3w+c)
__device__ __forceinline__ size_t prow(int t) {
    int b = t / (NN * 9);
    int r9 = t - b * (NN * 9);
    int n = r9 / 9, kk = r9 - n * 9;
    int h = n / WW, w = n - h * WW;
    int rr = kk / 3, c3 = kk - rr * 3;
    return ((size_t)b * (3 * HH) + 3 * h + rr) * (3 * WW) + 3 * w + c3;
}
// async global->LDS, 16B per lane; LDS dst = uniform base + lane*16
__device__ __forceinline__ void gl_lds16(const unsigned short* g, unsigned short* l) {
    __builtin_amdgcn_global_load_lds(
        (const __attribute__((address_space(1))) void*)g,
        (__attribute__((address_space(3))) void*)l, 16, 0, 0);
}

// ---------------- 128x128 GEMM (m97 structure) --------------------------------
// out[M,N] = A[M,K](bf16) @ Bt[N,K](bf16, pre-transposed) + bias; M,N,K mult of 128/128/32.
enum { EPI_F32 = 0, EPI_BF16 = 1, EPI_GELU = 2, EPI_RESID = 3, EPI_BF16PE = 4 };

template <int EPI>
__global__ __launch_bounds__(256) void gemm128(const unsigned short* __restrict__ A,
                                               const unsigned short* __restrict__ Bt,
                                               const float* __restrict__ bias,
                                               void* __restrict__ outp,
                                               int M, int N, int K, int row_off,
                                               const float* __restrict__ sp,
                                               const float* __restrict__ Epe) {
    __shared__ __align__(16) unsigned short As[128 * 32];
    __shared__ __align__(16) unsigned short Bs[128 * 32];
    const int tid  = threadIdx.x;
    const int wave = tid >> 6, lane = tid & 63;
    const int row0 = blockIdx.y * 128, col0 = blockIdx.x * 128;
    const int wm = wave >> 1, wn = wave & 1;          // 2x2 waves, 64x64 each
    const int lr = lane & 15, quad = lane >> 4;
    const int srow = lane >> 2;                       // 0..15
    const int scol = (lane & 3) * 8;                  // 0,8,16,24

    floatx4 acc[4][4] = {};

    const unsigned short* Abase = A + (size_t)row0 * K;
    const unsigned short* Bbase = Bt + (size_t)col0 * K;

    for (int kt = 0; kt < K; kt += 32) {
#pragma unroll
        for (int s = 0; s < 2; s++) {
            int chunk = s * 4 + wave;                 // 0..7, covers 16 rows each
            int r = chunk * 16 + srow;
            gl_lds16(Abase + (size_t)r * K + kt + scol, &As[chunk * 512]);
            gl_lds16(Bbase + (size_t)r * K + kt + scol, &Bs[chunk * 512]);
        }
        __syncthreads();
        short8 af[4], bf[4];
#pragma unroll
        for (int t = 0; t < 4; t++) {
            af[t] = *(const short8*)&As[(wm * 64 + t * 16 + lr) * 32 + quad * 8];
            bf[t] = *(const short8*)&Bs[(wn * 64 + t * 16 + lr) * 32 + quad * 8];
        }
#pragma unroll
        for (int mt = 0; mt < 4; mt++)
#pragma unroll
            for (int nt = 0; nt < 4; nt++)
                acc[mt][nt] = __builtin_amdgcn_mfma_f32_16x16x32_bf16(
                    af[mt], bf[nt], acc[mt][nt], 0, 0, 0);
        __syncthreads();
    }

    // C/D layout: col=lane&15, row=quad*4+reg  [verified m89/m91]
#pragma unroll
    for (int mt = 0; mt < 4; mt++) {
#pragma unroll
        for (int nt = 0; nt < 4; nt++) {
            int colg = col0 + wn * 64 + nt * 16 + lr;
            int rowb = row0 + wm * 64 + mt * 16 + quad * 4;
            float bv = bias[colg];
#pragma unroll
            for (int r = 0; r < 4; r++) {
                float vv = acc[mt][nt][r] + bv;
                if (EPI == EPI_F32) {
                    ((float*)outp)[(size_t)(rowb + r) * N + colg] = vv;
                } else if (EPI == EPI_BF16) {
                    ((unsigned short*)outp)[(size_t)(rowb + r) * N + colg] = f2bf(vv);
                } else if (EPI == EPI_GELU) {
                    ((unsigned short*)outp)[(size_t)(rowb + r) * N + colg] = f2bf(gelu_f(vv));
                } else if (EPI == EPI_RESID) {
                    size_t pr = prow(row_off + rowb + r);
                    ((float*)outp)[pr * (size_t)N + colg] += vv;
                } else {  // EPI_BF16PE
                    int t = rowb + r;
                    float gx = sp[(size_t)t * 2], gy = sp[(size_t)t * 2 + 1];
                    vv += gx * Epe[colg] + gy * Epe[CC + colg];
                    ((unsigned short*)outp)[(size_t)t * N + colg] = f2bf(vv);
                }
            }
        }
    }
}

// ---------------- weight transpose+convert: Wt[n][k] = bf16(W[k][n]) -----------
__global__ __launch_bounds__(256) void wprep_k(const float* __restrict__ W,
                                               unsigned short* __restrict__ Wt,
                                               int K, int N) {
    __shared__ float t[32][33];
    int n0 = blockIdx.x * 32, k0 = blockIdx.y * 32;
    int c = threadIdx.x & 31, r = threadIdx.x >> 5;   // 8 rows per pass
#pragma unroll
    for (int i = 0; i < 4; i++) {
        int kk = r + i * 8;
        t[kk][c] = W[(size_t)(k0 + kk) * N + n0 + c];
    }
    __syncthreads();
#pragma unroll
    for (int i = 0; i < 4; i++) {
        int nn = r + i * 8;
        Wt[(size_t)(n0 + nn) * K + k0 + c] = f2bf(t[c][nn]);
    }
}

// ---------------- fp32 -> bf16 convert (input) ---------------------------------
__global__ __launch_bounds__(256) void cvt_k(const float* __restrict__ x,
                                             unsigned short* __restrict__ y) {
    int i = blockIdx.x * 256 + threadIdx.x;
    float4 v = ((const float4*)x)[i];
    ushort4 o;
    o.x = f2bf(v.x); o.y = f2bf(v.y); o.z = f2bf(v.z); o.w = f2bf(v.w);
    ((ushort4*)y)[i] = o;
}

// ---------------- E/f precompute: E = ppw @ W (2xC), f = ppb @ W + b (C) -------
__global__ __launch_bounds__(256) void ef_k(const float* __restrict__ Wq,
                                            const float* __restrict__ bq,
                                            const float* __restrict__ Wk,
                                            const float* __restrict__ bk,
                                            const float* __restrict__ ppw,
                                            const float* __restrict__ ppb,
                                            float* __restrict__ buf) {
    const float* W = blockIdx.x ? Wk : Wq;
    const float* bs = blockIdx.x ? bk : bq;
    float* o = buf + (size_t)blockIdx.x * 3 * CC;
    int c = threadIdx.x;
    float e0 = 0.f, e1 = 0.f, f = 0.f;
    for (int k = 0; k < CC; k++) {
        float w = W[(size_t)k * CC + c];
        e0 += ppw[k] * w;
        e1 += ppw[CC + k] * w;
        f  += ppb[k] * w;
    }
    o[c] = e0; o[CC + c] = e1; o[2 * CC + c] = f + bs[c];
}

// ---------------- bilinear sample + positional encoding -----------------------
__global__ __launch_bounds__(256) void sample_k(const float* __restrict__ xmap,
                                                const float* __restrict__ sp,
                                                const float* __restrict__ ppw,
                                                const float* __restrict__ ppb,
                                                float* __restrict__ xw) {
    int t = blockIdx.x * 4 + (threadIdx.x >> 6);
    int lane = threadIdx.x & 63;
    int b = t / (NN * 9);

    const float* g = sp + (size_t)t * 2;
    float gxr = g[0], gyr = g[1];
    float gx = (gxr + 1.f) * (WW * 0.5f) - 0.5f;
    float gy = (gyr + 1.f) * (HH * 0.5f) - 0.5f;
    float x0f = floorf(gx), y0f = floorf(gy);
    int x0 = (int)x0f, y0 = (int)y0f;
    float wx1 = gx - x0f, wx0 = 1.f - wx1;
    float wy1 = gy - y0f, wy0 = 1.f - wy1;

    int ch = lane * 4;
    float a0 = 0.f, a1 = 0.f, a2 = 0.f, a3 = 0.f;
#pragma unroll
    for (int cc = 0; cc < 4; cc++) {
        int xx = x0 + (cc & 1), yy = y0 + (cc >> 1);
        float wgt = ((cc & 1) ? wx1 : wx0) * ((cc >> 1) ? wy1 : wy0);
        bool valid = (xx >= 0) && (xx < WW) && (yy >= 0) && (yy < HH);
        float m = valid ? wgt : 0.f;
        int xc = min(max(xx, 0), WW - 1), yc = min(max(yy, 0), HH - 1);
        const float* src = xmap + (((size_t)b * HH + yc) * WW + xc) * CC + ch;
        float4 vv = *(const float4*)src;
        a0 += m * vv.x; a1 += m * vv.y; a2 += m * vv.z; a3 += m * vv.w;
    }
    float p0 = gxr * ppw[ch + 0] + gyr * ppw[CC + ch + 0] + ppb[ch + 0];
    float p1 = gxr * ppw[ch + 1] + gyr * ppw[CC + ch + 1] + ppb[ch + 1];
    float p2 = gxr * ppw[ch + 2] + gyr * ppw[CC + ch + 2] + ppb[ch + 2];
    float p3 = gxr * ppw[ch + 3] + gyr * ppw[CC + ch + 3] + ppb[ch + 3];

    size_t o = prow(t) * CC + ch;
    float4 out; out.x = a0 + p0; out.y = a1 + p1; out.z = a2 + p2; out.w = a3 + p3;
    *(float4*)(xw + o) = out;
}

// ---------------- layernorm: 1 wave per 256-wide row ---------------------------
__global__ __launch_bounds__(256) void ln_k(const float* __restrict__ xw,
                                            const float* __restrict__ gamma,
                                            const float* __restrict__ beta,
                                            unsigned short* __restrict__ hh) {
    int row = blockIdx.x * 4 + (threadIdx.x >> 6);
    int lane = threadIdx.x & 63;
    size_t pr = prow(row);
    float4 xv = *(const float4*)(xw + pr * CC + lane * 4);
    float s = xv.x + xv.y + xv.z + xv.w;
    float sq = xv.x * xv.x + xv.y * xv.y + xv.z * xv.z + xv.w * xv.w;
#pragma unroll
    for (int off = 32; off; off >>= 1) {
        s += __shfl_xor(s, off);
        sq += __shfl_xor(sq, off);
    }
    float mean = s * (1.f / CC);
    float var = fmaxf(sq * (1.f / CC) - mean * mean, 0.f);
    float rs = rsqrtf(var + 1e-5f);

    float xs[4] = {xv.x, xv.y, xv.z, xv.w};
    ushort4 ho;
    unsigned short* hop = (unsigned short*)&ho;
#pragma unroll
    for (int ci = 0; ci < 4; ci++) {
        int c = lane * 4 + ci;
        hop[ci] = f2bf((xs[ci] - mean) * rs * gamma[c] + beta[c]);
    }
    *(ushort4*)(hh + (size_t)row * CC + lane * 4) = ho;
}

// ---------------- windowed attention ------------------------------------------
// 256 threads = 4 waves, one window per wave. k/v staged in LDS with layout
// [h][j][16dw], h-stride 148 dw -> head start banks {0,20,8,28,16,4,24,12}:
// conflict-free b128 reads. q kept packed (16 dwords). o in-place over q is
// safe: each (i,h) lane reads only its own q slice before writing it.
#define KVPAD 148
__global__ __launch_bounds__(256) void attn_k(const unsigned short* q,
                                              const unsigned short* __restrict__ k,
                                              const unsigned short* __restrict__ v,
                                              unsigned short* o) {
    __shared__ __align__(16) unsigned int lds[4 * 2 * 8 * KVPAD];  // 37888 B
    int wave = threadIdx.x >> 6, lane = threadIdx.x & 63;
    int w = blockIdx.x * 4 + wave;
    size_t base = (size_t)w * 9;
    unsigned int* ksu = lds + wave * (2 * 8 * KVPAD);
    unsigned int* vsu = ksu + 8 * KVPAD;
    const unsigned int* kg = (const unsigned int*)k;
    const unsigned int* vg = (const unsigned int*)v;
    for (int u = lane; u < 1152; u += 64) {
        int j = u >> 7, rem = u & 127;
        int h = rem >> 4, d2 = rem & 15;
        ksu[h * KVPAD + j * 16 + d2] = kg[(base + j) * 128 + rem];
        vsu[h * KVPAD + j * 16 + d2] = vg[(base + j) * 128 + rem];
    }
    __syncthreads();

    const float scale = 0.17677669529663687f;  // 1/sqrt(32)
    const unsigned int* qg = (const unsigned int*)q;
    unsigned int* og = (unsigned int*)o;

    for (int p = lane; p < 72; p += 64) {
        int i = p >> 3, h = p & 7;
        const uint4* qrow = (const uint4*)(qg + (base + i) * 128 + h * 16);
        uint4 qp[4];
        qp[0] = qrow[0]; qp[1] = qrow[1]; qp[2] = qrow[2]; qp[3] = qrow[3];
        const unsigned int* kh = ksu + h * KVPAD;
        const unsigned int* vh = vsu + h * KVPAD;

        float sc[9]; float mx = -1e30f;
#pragma unroll
        for (int j = 0; j < 9; j++) {
            float s = 0.f;
#pragma unroll
            for (int m = 0; m < 4; m++) {
                uint4 kk4 = *(const uint4*)(kh + j * 16 + m * 4);
                unsigned int qq[4] = {qp[m].x, qp[m].y, qp[m].z, qp[m].w};
                unsigned int kk[4] = {kk4.x, kk4.y, kk4.z, kk4.w};
#pragma unroll
                for (int d = 0; d < 4; d++) {
                    float qa, qb2, ka, kb2;
                    unp(qq[d], qa, qb2); unp(kk[d], ka, kb2);
                    s += qa * ka + qb2 * kb2;
                }
            }
            sc[j] = s * scale;
            mx = fmaxf(mx, sc[j]);
        }
        float den = 0.f;
#pragma unroll
        for (int j = 0; j < 9; j++) { sc[j] = __expf(sc[j] - mx); den += sc[j]; }
        float inv = 1.f / den;
#pragma unroll
        for (int j = 0; j < 9; j++) sc[j] *= inv;

#pragma unroll
        for (int m = 0; m < 4; m++) {
            float acc[8] = {};
#pragma unroll
            for (int j = 0; j < 9; j++) {
                uint4 vv4 = *(const uint4*)(vh + j * 16 + m * 4);
                unsigned int vvq[4] = {vv4.x, vv4.y, vv4.z, vv4.w};
#pragma unroll
                for (int d = 0; d < 4; d++) {
                    float va, vb2; unp(vvq[d], va, vb2);
                    acc[2 * d] += sc[j] * va;
                    acc[2 * d + 1] += sc[j] * vb2;
                }
            }
            uint4 ou;
            ou.x = pack2(acc[0], acc[1]); ou.y = pack2(acc[2], acc[3]);
            ou.z = pack2(acc[4], acc[5]); ou.w = pack2(acc[6], acc[7]);
            *(uint4*)(og + (base + i) * 128 + h * 16 + m * 4) = ou;
        }
    }
}

// ---------------- launcher ------------------------------------------------------
extern "C" void kernel_launch(void* const* d_in, const int* in_sizes, int n_in,
                              void* d_out, int out_size, void* d_ws, size_t ws_size,
                              hipStream_t stream) {
    const float* input = (const float*)d_in[0];
    const float* sp    = (const float*)d_in[1];
    const float* ipw   = (const float*)d_in[2];
    const float* ipb   = (const float*)d_in[3];
    const float* ppw   = (const float*)d_in[4];
    const float* ppb   = (const float*)d_in[5];
    const float* wq = (const float*)d_in[6];
    const float* bq = (const float*)d_in[7];
    const float* wk = (const float*)d_in[8];
    const float* bk = (const float*)d_in[9];
    const float* wv = (const float*)d_in[10];
    const float* bv = (const float*)d_in[11];
    const float* wo = (const float*)d_in[12];
    const float* bo = (const float*)d_in[13];
    const float* l1g = (const float*)d_in[14];
    const float* l1b = (const float*)d_in[15];
    const float* l2g = (const float*)d_in[16];
    const float* l2b = (const float*)d_in[17];
    const float* w1 = (const float*)d_in[18];
    const float* b1 = (const float*)d_in[19];
    const float* w2 = (const float*)d_in[20];
    const float* b2 = (const float*)d_in[21];

    float* xw = (float*)d_out;  // residual stream, rows permuted by prow()

    // workspace (~326 MB):
    //   [0, SZ_BF)        hh (bf16); early: xmap fp32 @0 (18.9MB), xbf @20MB (9.4MB)
    //   [SZ_BF, 2SZ_BF)   qb    -- FFN mid (bf16 [MC][FF]) overlays qb+kb
    //   [2SZ_BF, 3SZ_BF)  kb
    //   [3SZ_BF, 4SZ_BF)  vb
    //   [4SZ_BF, +8KB)    efbuf
    //   then weight buf: ipwt|wqt|wkt|wvt|wot|w1t|w2t (bf16, 1.7 MB)
    const size_t SZ_BF = (size_t)NTOK * CC * 2;  // 84,934,656
    char* ws = (char*)d_ws;
    unsigned short* hh  = (unsigned short*)ws;
    float* xmap         = (float*)ws;
    unsigned short* xbf = (unsigned short*)(ws + 20971520);
    unsigned short* qb  = (unsigned short*)(ws + SZ_BF);
    unsigned short* kb  = (unsigned short*)(ws + 2 * SZ_BF);
    unsigned short* vb  = (unsigned short*)(ws + 3 * SZ_BF);
    unsigned short* mid = (unsigned short*)(ws + SZ_BF);   // overlays qb,kb
    float* efbuf        = (float*)(ws + 4 * SZ_BF);
    unsigned short* wbuf = (unsigned short*)(ws + 4 * SZ_BF + 8192);
    unsigned short* ipwt = wbuf;
    unsigned short* wqt  = wbuf + 65536;
    unsigned short* wkt  = wbuf + 131072;
    unsigned short* wvt  = wbuf + 196608;
    unsigned short* wot  = wbuf + 262144;
    unsigned short* w1t  = wbuf + 327680;
    unsigned short* w2t  = wbuf + 589824;

    // input -> bf16; ipw -> transposed bf16; input projection; bilinear sample
    cvt_k<<<(BB * NN * CC / 4) / 256, 256, 0, stream>>>(input, xbf);
    wprep_k<<<dim3(CC / 32, CC / 32), 256, 0, stream>>>(ipw, ipwt, CC, CC);
    gemm128<EPI_F32><<<dim3(CC / 128, (BB * NN) / 128), 256, 0, stream>>>(
        xbf, ipwt, ipb, xmap, BB * NN, CC, CC, 0, nullptr, nullptr);
    sample_k<<<NTOK / 4, 256, 0, stream>>>(xmap, sp, ppw, ppb, xw);

    const int MC = NTOK / 2;  // 82944 = 648*128
    for (int l = 0; l < 2; l++) {
        const float* WQ = wq + (size_t)l * CC * CC;
        const float* WK = wk + (size_t)l * CC * CC;
        const float* WV = wv + (size_t)l * CC * CC;
        const float* WO = wo + (size_t)l * CC * CC;
        const float* W1 = w1 + (size_t)l * CC * FF;
        const float* W2 = w2 + (size_t)l * FF * CC;

        wprep_k<<<dim3(CC / 32, CC / 32), 256, 0, stream>>>(WQ, wqt, CC, CC);
        wprep_k<<<dim3(CC / 32, CC / 32), 256, 0, stream>>>(WK, wkt, CC, CC);
        wprep_k<<<dim3(CC / 32, CC / 32), 256, 0, stream>>>(WV, wvt, CC, CC);
        wprep_k<<<dim3(CC / 32, CC / 32), 256, 0, stream>>>(WO, wot, CC, CC);
        wprep_k<<<dim3(FF / 32, CC / 32), 256, 0, stream>>>(W1, w1t, CC, FF);
        wprep_k<<<dim3(CC / 32, FF / 32), 256, 0, stream>>>(W2, w2t, FF, CC);
        ef_k<<<2, 256, 0, stream>>>(WQ, bq + l * CC, WK, bk + l * CC, ppw, ppb, efbuf);

        ln_k<<<NTOK / 4, 256, 0, stream>>>(xw, l1g + l * CC, l1b + l * CC, hh);
        gemm128<EPI_BF16PE><<<dim3(CC / 128, NTOK / 128), 256, 0, stream>>>(
            hh, wqt, efbuf + 2 * CC, qb, NTOK, CC, CC, 0, sp, efbuf);
        gemm128<EPI_BF16PE><<<dim3(CC / 128, NTOK / 128), 256, 0, stream>>>(
            hh, wkt, efbuf + 5 * CC, kb, NTOK, CC, CC, 0, sp, efbuf + 3 * CC);
        gemm128<EPI_BF16><<<dim3(CC / 128, NTOK / 128), 256, 0, stream>>>(
            hh, wvt, bv + l * CC, vb, NTOK, CC, CC, 0, nullptr, nullptr);
        attn_k<<<NWIN / 4, 256, 0, stream>>>(qb, kb, vb, qb);  // o in-place
        gemm128<EPI_RESID><<<dim3(CC / 128, NTOK / 128), 256, 0, stream>>>(
            qb, wot, bo + l * CC, xw, NTOK, CC, CC, 0, nullptr, nullptr);
        ln_k<<<NTOK / 4, 256, 0, stream>>>(xw, l2g + l * CC, l2b + l * CC, hh);
        for (int cch = 0; cch < 2; cch++) {
            int m0 = cch * MC;
            gemm128<EPI_GELU><<<dim3(FF / 128, MC / 128), 256, 0, stream>>>(
                hh + (size_t)m0 * CC, w1t, b1 + l * FF, mid, MC, FF, CC, 0, nullptr, nullptr);
            gemm128<EPI_RESID><<<dim3(CC / 128, MC / 128), 256, 0, stream>>>(
                mid, w2t, b2 + l * CC, xw, MC, CC, FF, m0, nullptr, nullptr);
        }
    }
}

// Round 4
// 2490.378 us; speedup vs baseline: 2.8793x; 1.4180x over previous
//
#include <hip/hip_runtime.h>
#include <math.h>

// ---------------- constants ----------------
#define BB    2
#define HH    96
#define WW    96
#define CC    256
#define NHEAD 8
#define DH    32
#define NN    (HH*WW)          // 9216
#define NWIN  (BB*NN)          // 18432 windows of 9 tokens
#define NTOK  (NWIN*9)         // 165888 tokens
#define FF    1024

typedef __attribute__((ext_vector_type(8))) short short8;
typedef __attribute__((ext_vector_type(4))) float floatx4;

__device__ __forceinline__ float bf2f(unsigned short u) {
    union { unsigned int i; float f; } c; c.i = ((unsigned int)u) << 16; return c.f;
}
__device__ __forceinline__ unsigned short f2bf(float f) {
    union { unsigned int i; float f; } c; c.f = f;
    unsigned int i = c.i;
    return (unsigned short)((i + 0x7FFFu + ((i >> 16) & 1u)) >> 16);
}
__device__ __forceinline__ unsigned int pack2(float a, float b) {
    return (unsigned int)f2bf(a) | ((unsigned int)f2bf(b) << 16);
}
__device__ __forceinline__ float blo(unsigned int u) {
    union { unsigned int i; float f; } c; c.i = u << 16; return c.f;
}
__device__ __forceinline__ float bhi(unsigned int u) {
    union { unsigned int i; float f; } c; c.i = u & 0xffff0000u; return c.f;
}
__device__ __forceinline__ float gelu_f(float v) {
    float y = 0.7978845608028654f * (v + 0.044715f * v * v * v);
    float t = 1.f - 2.f / (1.f + __expf(2.f * y));   // tanh(y)
    return 0.5f * v * (1.f + t);
}
// token t=(b, n=h*W+w, kk=r*3+c) -> physical output row (b, 3h+r, 3w+c)
__device__ __forceinline__ size_t prow(int t) {
    int b = t / (NN * 9);
    int r9 = t - b * (NN * 9);
    int n = r9 / 9, kk = r9 - n * 9;
    int h = n / WW, w = n - h * WW;
    int rr = kk / 3, c3 = kk - rr * 3;
    return ((size_t)b * (3 * HH) + 3 * h + rr) * (3 * WW) + 3 * w + c3;
}
// async global->LDS, 16B per lane; LDS dst = uniform base + lane*16
__device__ __forceinline__ void gl_lds16(const unsigned short* g, unsigned short* l) {
    __builtin_amdgcn_global_load_lds(
        (const __attribute__((address_space(1))) void*)g,
        (__attribute__((address_space(3))) void*)l, 16, 0, 0);
}

// ---------------- 128x128 GEMM (m97 structure) --------------------------------
// out[M,N] = A[M,K](bf16, row stride lda) @ Bt[N,K](bf16) + bias.
enum { EPI_F32 = 0, EPI_BF16 = 1, EPI_GELU = 2, EPI_RESID = 3, EPI_BF16PE = 4 };

template <int EPI>
__global__ __launch_bounds__(256) void gemm128(const unsigned short* __restrict__ A,
                                               const unsigned short* __restrict__ Bt,
                                               const float* __restrict__ bias,
                                               void* __restrict__ outp,
                                               int M, int N, int K, int lda, int row_off,
                                               const float* __restrict__ sp,
                                               const float* __restrict__ Epe) {
    __shared__ __align__(16) unsigned short As[128 * 32];
    __shared__ __align__(16) unsigned short Bs[128 * 32];
    const int tid  = threadIdx.x;
    const int wave = tid >> 6, lane = tid & 63;
    const int row0 = blockIdx.y * 128, col0 = blockIdx.x * 128;
    const int wm = wave >> 1, wn = wave & 1;          // 2x2 waves, 64x64 each
    const int lr = lane & 15, quad = lane >> 4;
    const int srow = lane >> 2;                       // 0..15
    const int scol = (lane & 3) * 8;                  // 0,8,16,24

    floatx4 acc[4][4] = {};

    const unsigned short* Abase = A + (size_t)row0 * lda;
    const unsigned short* Bbase = Bt + (size_t)col0 * K;

    for (int kt = 0; kt < K; kt += 32) {
#pragma unroll
        for (int s = 0; s < 2; s++) {
            int chunk = s * 4 + wave;                 // 0..7, 16 rows each
            int r = chunk * 16 + srow;
            gl_lds16(Abase + (size_t)r * lda + kt + scol, &As[chunk * 512]);
            gl_lds16(Bbase + (size_t)r * K + kt + scol, &Bs[chunk * 512]);
        }
        __syncthreads();
        short8 af[4], bf[4];
#pragma unroll
        for (int t = 0; t < 4; t++) {
            af[t] = *(const short8*)&As[(wm * 64 + t * 16 + lr) * 32 + quad * 8];
            bf[t] = *(const short8*)&Bs[(wn * 64 + t * 16 + lr) * 32 + quad * 8];
        }
#pragma unroll
        for (int mt = 0; mt < 4; mt++)
#pragma unroll
            for (int nt = 0; nt < 4; nt++)
                acc[mt][nt] = __builtin_amdgcn_mfma_f32_16x16x32_bf16(
                    af[mt], bf[nt], acc[mt][nt], 0, 0, 0);
        __syncthreads();
    }

    // C/D layout: col=lane&15, row=quad*4+reg  [verified m89/m91]
#pragma unroll
    for (int mt = 0; mt < 4; mt++) {
#pragma unroll
        for (int nt = 0; nt < 4; nt++) {
            int colg = col0 + wn * 64 + nt * 16 + lr;
            int rowb = row0 + wm * 64 + mt * 16 + quad * 4;
            float bv = bias[colg];
#pragma unroll
            for (int r = 0; r < 4; r++) {
                float vv = acc[mt][nt][r] + bv;
                if (EPI == EPI_F32) {
                    ((float*)outp)[(size_t)(rowb + r) * N + colg] = vv;
                } else if (EPI == EPI_BF16) {
                    ((unsigned short*)outp)[(size_t)(rowb + r) * N + colg] = f2bf(vv);
                } else if (EPI == EPI_GELU) {
                    ((unsigned short*)outp)[(size_t)(rowb + r) * N + colg] = f2bf(gelu_f(vv));
                } else if (EPI == EPI_RESID) {
                    size_t pr = prow(row_off + rowb + r);
                    ((float*)outp)[pr * (size_t)N + colg] += vv;
                } else {  // EPI_BF16PE: rank-2 positional correction, Epe width N
                    int t = rowb + r;
                    float gx = sp[(size_t)t * 2], gy = sp[(size_t)t * 2 + 1];
                    vv += gx * Epe[colg] + gy * Epe[N + colg];
                    ((unsigned short*)outp)[(size_t)t * N + colg] = f2bf(vv);
                }
            }
        }
    }
}

// ---------------- 32x32 transpose+convert tile body ----------------------------
__device__ __forceinline__ void wtile(const float* __restrict__ src,
                                      unsigned short* __restrict__ dst,
                                      int K, int N, int tile) {
    __shared__ float t[32][33];
    int n0 = (tile % (N / 32)) * 32, k0 = (tile / (N / 32)) * 32;
    int c = threadIdx.x & 31, r = threadIdx.x >> 5;
#pragma unroll
    for (int i = 0; i < 4; i++) {
        int kk = r + i * 8;
        t[kk][c] = src[(size_t)(k0 + kk) * N + n0 + c];
    }
    __syncthreads();
#pragma unroll
    for (int i = 0; i < 4; i++) {
        int nn = r + i * 8;
        dst[(size_t)(n0 + nn) * K + k0 + c] = f2bf(t[c][nn]);
    }
}

__global__ __launch_bounds__(256) void wprep_k(const float* __restrict__ W,
                                               unsigned short* __restrict__ Wt,
                                               int K, int N) {
    wtile(W, Wt, K, N, blockIdx.x);
}

// per-layer weight prep: qkvt | wot | w1t | w2t  (768 tiles)
__global__ __launch_bounds__(256) void wprep_all(const float* __restrict__ wq,
                                                 const float* __restrict__ wk,
                                                 const float* __restrict__ wv,
                                                 const float* __restrict__ wo,
                                                 const float* __restrict__ w1,
                                                 const float* __restrict__ w2,
                                                 unsigned short* __restrict__ wbuf,
                                                 int l) {
    int bid = blockIdx.x;
    const float* src; unsigned short* dst; int K, N, tile;
    if (bid < 256) {
        int which = bid >> 6; tile = bid & 63;
        src = (which == 0 ? wq : which == 1 ? wk : which == 2 ? wv : wo)
              + (size_t)l * CC * CC;
        dst = wbuf + (which < 3 ? which * 65536 : 196608);
        K = CC; N = CC;
    } else if (bid < 512) {
        tile = bid - 256; src = w1 + (size_t)l * CC * FF; dst = wbuf + 262144;
        K = CC; N = FF;
    } else {
        tile = bid - 512; src = w2 + (size_t)l * FF * CC; dst = wbuf + 524288;
        K = FF; N = CC;
    }
    wtile(src, dst, K, N, tile);
}

// ---------------- fp32 -> bf16 convert (input) ---------------------------------
__global__ __launch_bounds__(256) void cvt_k(const float* __restrict__ x,
                                             unsigned short* __restrict__ y) {
    int i = blockIdx.x * 256 + threadIdx.x;
    float4 v = ((const float4*)x)[i];
    ushort4 o;
    o.x = f2bf(v.x); o.y = f2bf(v.y); o.z = f2bf(v.z); o.w = f2bf(v.w);
    ((ushort4*)y)[i] = o;
}

// ---------------- E/f precompute for fused QKV ---------------------------------
// ef[l] = [e0 row(768) | e1 row(768) | f row(768)]; cols 0-255=Q, 256-511=K,
// 512-767=V (e=0, f=bv).
__global__ __launch_bounds__(256) void ef_all(const float* __restrict__ wq,
                                              const float* __restrict__ bq,
                                              const float* __restrict__ wk,
                                              const float* __restrict__ bk,
                                              const float* __restrict__ bv,
                                              const float* __restrict__ ppw,
                                              const float* __restrict__ ppb,
                                              float* __restrict__ ef) {
    int l = blockIdx.x / 3;
    int c = (blockIdx.x % 3) * 256 + threadIdx.x;
    float* o = ef + (size_t)l * 2304;
    float e0 = 0.f, e1 = 0.f, f = 0.f;
    if (c < 512) {
        const float* W = (c < 256 ? wq : wk) + (size_t)l * CC * CC;
        const float* bb = (c < 256 ? bq : bk) + l * CC;
        int cc = c & 255;
        for (int k = 0; k < CC; k++) {
            float w = W[(size_t)k * CC + cc];
            e0 += ppw[k] * w; e1 += ppw[CC + k] * w; f += ppb[k] * w;
        }
        f += bb[cc];
    } else {
        f = bv[l * CC + (c - 512)];
    }
    o[c] = e0; o[768 + c] = e1; o[1536 + c] = f;
}

// ---------------- bilinear sample + positional encoding -----------------------
__global__ __launch_bounds__(256) void sample_k(const float* __restrict__ xmap,
                                                const float* __restrict__ sp,
                                                const float* __restrict__ ppw,
                                                const float* __restrict__ ppb,
                                                float* __restrict__ xw) {
    int t = blockIdx.x * 4 + (threadIdx.x >> 6);
    int lane = threadIdx.x & 63;
    int b = t / (NN * 9);

    const float* g = sp + (size_t)t * 2;
    float gxr = g[0], gyr = g[1];
    float gx = (gxr + 1.f) * (WW * 0.5f) - 0.5f;
    float gy = (gyr + 1.f) * (HH * 0.5f) - 0.5f;
    float x0f = floorf(gx), y0f = floorf(gy);
    int x0 = (int)x0f, y0 = (int)y0f;
    float wx1 = gx - x0f, wx0 = 1.f - wx1;
    float wy1 = gy - y0f, wy0 = 1.f - wy1;

    int ch = lane * 4;
    float a0 = 0.f, a1 = 0.f, a2 = 0.f, a3 = 0.f;
#pragma unroll
    for (int cc = 0; cc < 4; cc++) {
        int xx = x0 + (cc & 1), yy = y0 + (cc >> 1);
        float wgt = ((cc & 1) ? wx1 : wx0) * ((cc >> 1) ? wy1 : wy0);
        bool valid = (xx >= 0) && (xx < WW) && (yy >= 0) && (yy < HH);
        float m = valid ? wgt : 0.f;
        int xc = min(max(xx, 0), WW - 1), yc = min(max(yy, 0), HH - 1);
        const float* src = xmap + (((size_t)b * HH + yc) * WW + xc) * CC + ch;
        float4 vv = *(const float4*)src;
        a0 += m * vv.x; a1 += m * vv.y; a2 += m * vv.z; a3 += m * vv.w;
    }
    float p0 = gxr * ppw[ch + 0] + gyr * ppw[CC + ch + 0] + ppb[ch + 0];
    float p1 = gxr * ppw[ch + 1] + gyr * ppw[CC + ch + 1] + ppb[ch + 1];
    float p2 = gxr * ppw[ch + 2] + gyr * ppw[CC + ch + 2] + ppb[ch + 2];
    float p3 = gxr * ppw[ch + 3] + gyr * ppw[CC + ch + 3] + ppb[ch + 3];

    size_t o = prow(t) * CC + ch;
    float4 out; out.x = a0 + p0; out.y = a1 + p1; out.z = a2 + p2; out.w = a3 + p3;
    *(float4*)(xw + o) = out;
}

// ---------------- layernorm: 1 wave per 256-wide row ---------------------------
__global__ __launch_bounds__(256) void ln_k(const float* __restrict__ xw,
                                            const float* __restrict__ gamma,
                                            const float* __restrict__ beta,
                                            unsigned short* __restrict__ hh) {
    int row = blockIdx.x * 4 + (threadIdx.x >> 6);
    int lane = threadIdx.x & 63;
    size_t pr = prow(row);
    float4 xv = *(const float4*)(xw + pr * CC + lane * 4);
    float s = xv.x + xv.y + xv.z + xv.w;
    float sq = xv.x * xv.x + xv.y * xv.y + xv.z * xv.z + xv.w * xv.w;
#pragma unroll
    for (int off = 32; off; off >>= 1) {
        s += __shfl_xor(s, off);
        sq += __shfl_xor(sq, off);
    }
    float mean = s * (1.f / CC);
    float var = fmaxf(sq * (1.f / CC) - mean * mean, 0.f);
    float rs = rsqrtf(var + 1e-5f);

    float xs[4] = {xv.x, xv.y, xv.z, xv.w};
    ushort4 ho;
    unsigned short* hop = (unsigned short*)&ho;
#pragma unroll
    for (int ci = 0; ci < 4; ci++) {
        int c = lane * 4 + ci;
        hop[ci] = f2bf((xs[ci] - mean) * rs * gamma[c] + beta[c]);
    }
    *(ushort4*)(hh + (size_t)row * CC + lane * 4) = ho;
}

// ---------------- windowed attention (qkv interleaved [t][q|k|v]) --------------
// 2 windows/block, 128 thr/window, one (i,h) task/thread. LDS layout [h][j]
// padded to 148 dw/head: k/v compute reads are same-address broadcasts (0
// conflicts). o overwrites the q LDS region, then streams out coalesced.
// __launch_bounds__(256,4) caps VGPR at 128 -> no scratch spill.
#define KVP 148
__global__ __launch_bounds__(256, 4) void attn_k(unsigned int* qkv) {
    __shared__ unsigned int lds[2 * 3552];   // 28416 B
    const int g = threadIdx.x >> 7, t = threadIdx.x & 127;
    const int w = blockIdx.x * 2 + g;
    const size_t tok0 = (size_t)w * 9;
    unsigned int* L = lds + g * 3552;        // [q:0][k:+1184][v:+2368]
    const uint4* src = (const uint4*)(qkv + tok0 * 384);
    for (int u = t; u < 864; u += 128) {     // 9 tok x 96 u4, contiguous
        int j = u / 96, rem = u - j * 96;
        int sub = rem >> 5, r2 = rem & 31, h = r2 >> 2, q4 = r2 & 3;
        uint4 val = src[u];
        *(uint4*)(L + sub * 1184 + h * KVP + j * 16 + q4 * 4) = val;
    }
    __syncthreads();
    if (t < 72) {
        const int i = t >> 3, h = t & 7;
        unsigned int* qh = L + h * KVP + i * 16;
        const unsigned int* kh = L + 1184 + h * KVP;
        const unsigned int* vh = L + 2368 + h * KVP;
        uint4 qp[4];
        qp[0] = *(const uint4*)qh;        qp[1] = *(const uint4*)(qh + 4);
        qp[2] = *(const uint4*)(qh + 8);  qp[3] = *(const uint4*)(qh + 12);
        float sc[9], mx = -1e30f;
#pragma unroll
        for (int j = 0; j < 9; j++) {
            float s = 0.f;
#pragma unroll
            for (int m = 0; m < 4; m++) {
                uint4 kk = *(const uint4*)(kh + j * 16 + m * 4);
                unsigned int qa[4] = {qp[m].x, qp[m].y, qp[m].z, qp[m].w};
                unsigned int ka[4] = {kk.x, kk.y, kk.z, kk.w};
#pragma unroll
                for (int d = 0; d < 4; d++)
                    s += blo(qa[d]) * blo(ka[d]) + bhi(qa[d]) * bhi(ka[d]);
            }
            sc[j] = s * 0.17677669529663687f;   // 1/sqrt(32)
            mx = fmaxf(mx, sc[j]);
        }
        float den = 0.f;
#pragma unroll
        for (int j = 0; j < 9; j++) { sc[j] = __expf(sc[j] - mx); den += sc[j]; }
        float inv = 1.f / den;
#pragma unroll
        for (int j = 0; j < 9; j++) sc[j] *= inv;
#pragma unroll
        for (int m = 0; m < 4; m++) {
            float a[8] = {};
#pragma unroll
            for (int j = 0; j < 9; j++) {
                uint4 vv = *(const uint4*)(vh + j * 16 + m * 4);
                unsigned int va[4] = {vv.x, vv.y, vv.z, vv.w};
#pragma unroll
                for (int d = 0; d < 4; d++) {
                    a[2 * d]     += sc[j] * blo(va[d]);
                    a[2 * d + 1] += sc[j] * bhi(va[d]);
                }
            }
            uint4 ou;
            ou.x = pack2(a[0], a[1]); ou.y = pack2(a[2], a[3]);
            ou.z = pack2(a[4], a[5]); ou.w = pack2(a[6], a[7]);
            *(uint4*)(qh + m * 4) = ou;    // o over own q slice
        }
    }
    __syncthreads();
    uint4* dst = (uint4*)(qkv + tok0 * 384);
    for (int u = t; u < 288; u += 128) {   // o -> q slice, coalesced full lines
        int j = u >> 5, rem = u & 31, h2 = rem >> 2, q4 = rem & 3;
        dst[j * 96 + rem] = *(const uint4*)(L + h2 * KVP + j * 16 + q4 * 4);
    }
}

// ---------------- launcher ------------------------------------------------------
extern "C" void kernel_launch(void* const* d_in, const int* in_sizes, int n_in,
                              void* d_out, int out_size, void* d_ws, size_t ws_size,
                              hipStream_t stream) {
    const float* input = (const float*)d_in[0];
    const float* sp    = (const float*)d_in[1];
    const float* ipw   = (const float*)d_in[2];
    const float* ipb   = (const float*)d_in[3];
    const float* ppw   = (const float*)d_in[4];
    const float* ppb   = (const float*)d_in[5];
    const float* wq = (const float*)d_in[6];
    const float* bq = (const float*)d_in[7];
    const float* wk = (const float*)d_in[8];
    const float* bk = (const float*)d_in[9];
    const float* wv = (const float*)d_in[10];
    const float* bv = (const float*)d_in[11];
    const float* wo = (const float*)d_in[12];
    const float* bo = (const float*)d_in[13];
    const float* l1g = (const float*)d_in[14];
    const float* l1b = (const float*)d_in[15];
    const float* l2g = (const float*)d_in[16];
    const float* l2b = (const float*)d_in[17];
    const float* w1 = (const float*)d_in[18];
    const float* b1 = (const float*)d_in[19];
    const float* w2 = (const float*)d_in[20];
    const float* b2 = (const float*)d_in[21];

    float* xw = (float*)d_out;  // residual stream, rows permuted by prow()

    // workspace (~341.5 MB):
    //   [0, SZ_BF)          hh (bf16); early: xmap fp32 @0, xbf @20MB
    //   [SZ_BF, 4SZ_BF)     qkv bf16 [NTOK][768]  -- FFN mid overlays
    //   [4SZ_BF, +18KB)     ef (2 layers x 3 x 768 fp32)
    //   then wbuf: qkvt|wot|w1t|w2t (per-layer, reused) + ipwt  (1.7 MB)
    const size_t SZ_BF = (size_t)NTOK * CC * 2;  // 84,934,656
    char* ws = (char*)d_ws;
    unsigned short* hh  = (unsigned short*)ws;
    float* xmap         = (float*)ws;
    unsigned short* xbf = (unsigned short*)(ws + 20971520);
    unsigned short* qkv = (unsigned short*)(ws + SZ_BF);
    unsigned short* mid = (unsigned short*)(ws + SZ_BF);   // overlays qkv
    float* ef           = (float*)(ws + 4 * SZ_BF);
    unsigned short* wbuf = (unsigned short*)(ws + 4 * SZ_BF + 18432);
    unsigned short* qkvt = wbuf;                 // 196608
    unsigned short* wot  = wbuf + 196608;        // 65536
    unsigned short* w1t  = wbuf + 262144;        // 262144
    unsigned short* w2t  = wbuf + 524288;        // 262144
    unsigned short* ipwt = wbuf + 786432;        // 65536

    cvt_k<<<(BB * NN * CC / 4) / 256, 256, 0, stream>>>(input, xbf);
    wprep_k<<<64, 256, 0, stream>>>(ipw, ipwt, CC, CC);
    ef_all<<<6, 256, 0, stream>>>(wq, bq, wk, bk, bv, ppw, ppb, ef);
    gemm128<EPI_F32><<<dim3(CC / 128, (BB * NN) / 128), 256, 0, stream>>>(
        xbf, ipwt, ipb, xmap, BB * NN, CC, CC, CC, 0, nullptr, nullptr);
    sample_k<<<NTOK / 4, 256, 0, stream>>>(xmap, sp, ppw, ppb, xw);

    const int MC = NTOK / 2;  // 82944 = 648*128
    for (int l = 0; l < 2; l++) {
        wprep_all<<<768, 256, 0, stream>>>(wq, wk, wv, wo, w1, w2, qkvt, l);

        ln_k<<<NTOK / 4, 256, 0, stream>>>(xw, l1g + l * CC, l1b + l * CC, hh);
        // fused QKV: [NTOK,256] @ [256,768] -> qkv interleaved, PE in epilogue
        gemm128<EPI_BF16PE><<<dim3(768 / 128, NTOK / 128), 256, 0, stream>>>(
            hh, qkvt, ef + (size_t)l * 2304 + 1536, qkv, NTOK, 768, CC, CC, 0,
            sp, ef + (size_t)l * 2304);
        attn_k<<<NWIN / 2, 256, 0, stream>>>((unsigned int*)qkv);
        gemm128<EPI_RESID><<<dim3(CC / 128, NTOK / 128), 256, 0, stream>>>(
            qkv, wot, bo + l * CC, xw, NTOK, CC, CC, 768, 0, nullptr, nullptr);
        ln_k<<<NTOK / 4, 256, 0, stream>>>(xw, l2g + l * CC, l2b + l * CC, hh);
        for (int cch = 0; cch < 2; cch++) {
            int m0 = cch * MC;
            gemm128<EPI_GELU><<<dim3(FF / 128, MC / 128), 256, 0, stream>>>(
                hh + (size_t)m0 * CC, w1t, b1 + l * FF, mid, MC, FF, CC, CC, 0,
                nullptr, nullptr);
            gemm128<EPI_RESID><<<dim3(CC / 128, MC / 128), 256, 0, stream>>>(
                mid, w2t, b2 + l * CC, xw, MC, CC, FF, FF, m0, nullptr, nullptr);
        }
    }
}